// Round 4
// baseline (464.566 us; speedup 1.0000x reference)
//
#include <hip/hip_runtime.h>
#include <math.h>

#define NS 4096
#define NF 512
#define NB 16
#define NC 10
#define HS 8192           // hash slots, load factor 0.5
#define HEMPTY 0xFFFFFFFFu

// ws layout (proven size in R2): float stats[8192][16] = 512 KB, then int counts[16][10]
// stats slot: 0 sum, 1 sumsq, 2 sumabs, 3 nancnt, 4 maxabs(int-bits), 5..14 csum
#define STATS_BYTES (NB * NF * 16 * 4)

// ---------------- K1: coalesced moments + class-sums + class-counts ----------------
// grid = 16 b x 16 sc x 2 fh = 512 blocks; thread owns one feature, walks 256 rows.
// y is wave-uniform -> class dispatch is scalar branches, ~1 VALU add per element.
__launch_bounds__(256)
__global__ void stats_pass_kernel(const float* __restrict__ X,
                                  const int* __restrict__ y,
                                  float* __restrict__ statsb,
                                  int* __restrict__ counts) {
    __shared__ int hist[NC];
    const int w  = blockIdx.x;
    const int b  = w >> 5;
    const int sc = (w >> 1) & 15;
    const int fh = w & 1;
    const int tid = threadIdx.x;
    const int f  = fh * 256 + tid;

    // fold per-(b) class counts in (only one fh-half contributes)
    if (fh == 0) {
        if (tid < NC) hist[tid] = 0;
        __syncthreads();
        atomicAdd(&hist[y[b * NS + sc * 256 + tid]], 1);
        __syncthreads();
        if (tid < NC) atomicAdd(&counts[b * NC + tid], hist[tid]);
    }

    const float* Xp = X + ((size_t)b * NS + (size_t)sc * 256) * NF + f;
    const int*   yp = y + b * NS + sc * 256;

    float sum = 0.f, sumsq = 0.f, sumabs = 0.f, nancnt = 0.f, maxab = 0.f;
    float cs[NC];
    #pragma unroll
    for (int c = 0; c < NC; c++) cs[c] = 0.f;

    for (int r0 = 0; r0 < 256; r0 += 8) {
        float xv[8];
        #pragma unroll
        for (int k = 0; k < 8; k++) xv[k] = Xp[(size_t)(r0 + k) * NF];   // 8 coalesced loads in flight
        #pragma unroll
        for (int k = 0; k < 8; k++) {
            float x = xv[k];
            const int yv = __builtin_amdgcn_readfirstlane(yp[r0 + k]);   // wave-uniform -> SGPR
            if (x != x) { nancnt += 1.f; x = 0.f; }
            sum += x;
            sumsq = fmaf(x, x, sumsq);
            const float a = fabsf(x);
            sumabs += a;
            maxab = fmaxf(maxab, a);
            #pragma unroll
            for (int c = 0; c < NC; c++)
                if (yv == c) cs[c] += x;                                 // scalar-branch guarded
        }
    }

    float* sp = statsb + ((size_t)(b * NF + f)) * 16;
    atomicAdd(sp + 0, sum);
    atomicAdd(sp + 1, sumsq);
    atomicAdd(sp + 2, sumabs);
    atomicAdd(sp + 3, nancnt);
    atomicMax((int*)(sp + 4), __float_as_int(maxab));   // maxab >= 0: int order == float order
    #pragma unroll
    for (int c = 0; c < NC; c++) atomicAdd(sp + 5 + c, cs[c]);
}

// ---------------- K2: per-column hash unique + finalize + MLP ----------------
__device__ __forceinline__ int wave_reduce_add_i(int v) {
    #pragma unroll
    for (int off = 32; off > 0; off >>= 1) v += __shfl_down(v, off, 64);
    return v;
}

// 512 threads/block, 4 blocks/CU (32 waves = 100% occupancy), 8 elements/thread
__launch_bounds__(512, 8)
__global__ void unique_mlp_kernel(const float* __restrict__ X,
                                  const float* __restrict__ statsb,
                                  const int* __restrict__ counts,
                                  const float* __restrict__ w1,
                                  const float* __restrict__ b1,
                                  const float* __restrict__ w2,
                                  const float* __restrict__ b2,
                                  float* __restrict__ out) {
    __shared__ unsigned int hash[HS];   // 32 KB
    __shared__ float redu[8];
    __shared__ float stats_s[6];
    __shared__ float h_s[64];

    const int w = blockIdx.x;
    const int g = (w & 7) * 1024 + (w >> 3);   // XCD swizzle: adjacent columns share an XCD's L2
    const int b = g >> 9;
    const int f = g & (NF - 1);
    const int tid = threadIdx.x;

    {
        uint4* hp = (uint4*)hash;
        #pragma unroll
        for (int i = 0; i < (HS / 4) / 512; i++)
            hp[tid + i * 512] = make_uint4(HEMPTY, HEMPTY, HEMPTY, HEMPTY);
    }
    __syncthreads();

    const float* Xp = X + (size_t)b * NS * NF + f;

    float xv[8];
    #pragma unroll
    for (int k = 0; k < 8; k++)                   // all 8 strided loads in flight
        xv[k] = Xp[(size_t)(k * 512 + tid) * NF];

    int uniq = 0;
    #pragma unroll
    for (int k = 0; k < 8; k++) {
        float x = xv[k];
        if (x != x) x = 0.f;                      // nan_to_num before unique-count
        unsigned int pat = __float_as_uint(x);
        if (pat == 0x80000000u) pat = 0u;         // -0.0 == +0.0
        unsigned int slot = (pat * 2654435761u) >> 19;   // top 13 bits -> [0, 8192)
        for (;;) {
            const unsigned int old = atomicCAS(&hash[slot], HEMPTY, pat);
            if (old == HEMPTY) { uniq++; break; }
            if (old == pat) break;
            slot = (slot + 1) & (HS - 1);
        }
    }

    const int wave = tid >> 6, lane = tid & 63;
    const int u = wave_reduce_add_i(uniq);
    if (lane == 0) redu[wave] = (float)u;
    __syncthreads();

    if (tid == 0) {
        float n_unique = 0.f;
        #pragma unroll
        for (int i = 0; i < 8; i++) n_unique += redu[i];
        const float* sp = statsb + (size_t)g * 16;
        const float invS = 1.f / (float)NS;
        const float gmean    = sp[0] * invS;
        const float variance = fmaxf(sp[1] * invS - gmean * gmean, 0.f);
        const float mean_abs = sp[2] * invS;
        const float missing  = sp[3] * invS;
        const float max_abs  = sp[4];             // stored as float bits via atomicMax(int)
        float between = 0.f;
        #pragma unroll
        for (int c = 0; c < NC; c++) {
            const float cnt = (float)counts[b * NC + c];
            const float cm  = sp[5 + c] / fmaxf(cnt, 1.f);
            const float d   = cm - gmean;
            between += cnt * d * d;
        }
        between *= invS;
        const float target = between / fmaxf(variance, 1e-6f);
        float st[6] = { target, missing, n_unique * invS, variance, mean_abs, max_abs };
        #pragma unroll
        for (int i = 0; i < 6; i++) {
            float v = st[i];
            if (!(fabsf(v) < INFINITY)) v = 0.f;  // nan_to_num
            stats_s[i] = v;
        }
    }
    __syncthreads();

    if (tid < 64) {
        float z = b1[tid];
        #pragma unroll
        for (int i = 0; i < 6; i++) z = fmaf(stats_s[i], w1[i * 64 + tid], z);
        h_s[tid] = 0.5f * z * (1.f + erff(z * 0.70710678118654752440f));
    }
    __syncthreads();
    if (tid < 128) {
        float o = b2[tid];
        #pragma unroll
        for (int j = 0; j < 64; j++) o = fmaf(h_s[j], w2[j * 128 + tid], o);
        out[(size_t)g * 128 + tid] = o;
    }
}

extern "C" void kernel_launch(void* const* d_in, const int* in_sizes, int n_in,
                              void* d_out, int out_size, void* d_ws, size_t ws_size,
                              hipStream_t stream) {
    const float* X  = (const float*)d_in[0];
    const int*   y  = (const int*)d_in[1];
    const float* w1 = (const float*)d_in[2];
    const float* b1 = (const float*)d_in[3];
    const float* w2 = (const float*)d_in[4];
    const float* b2 = (const float*)d_in[5];
    float* out    = (float*)d_out;
    float* statsb = (float*)d_ws;
    int*   counts = (int*)((char*)d_ws + STATS_BYTES);

    hipMemsetAsync(d_ws, 0, STATS_BYTES + NB * NC * 4, stream);
    stats_pass_kernel<<<NB * 16 * 2, 256, 0, stream>>>(X, y, statsb, counts);
    unique_mlp_kernel<<<NB * NF, 512, 0, stream>>>(X, statsb, counts, w1, b1, w2, b2, out);
}